// Round 8
// baseline (184.680 us; speedup 1.0000x reference)
//
#include <hip/hip_runtime.h>
#include <stdint.h>

// ---- types ----
typedef short s16x8 __attribute__((ext_vector_type(8)));
typedef float f32x4 __attribute__((ext_vector_type(4)));
typedef unsigned int u32x4 __attribute__((ext_vector_type(4)));

// log2(e) / sqrt(128): fold softmax scale + exp2 conversion into Q projection
#define QSCALE 0.12751743f

__device__ __forceinline__ unsigned short f2bf(float f) {
  unsigned int u = __builtin_bit_cast(unsigned int, f);
  u += 0x7fffu + ((u >> 16) & 1u);   // RNE
  return (unsigned short)(u >> 16);
}

__device__ __forceinline__ f32x4 mfma16(s16x8 a, s16x8 b, f32x4 c) {
  return __builtin_amdgcn_mfma_f32_16x16x32_bf16(a, b, c, 0, 0, 0);
}

// async global->LDS DMA, 16B/lane, dest = wave-uniform base + lane*16
#define GLD(GP, LP)                                                            \
  __builtin_amdgcn_global_load_lds(                                            \
      (const __attribute__((address_space(1))) unsigned int*)(GP),             \
      (__attribute__((address_space(3))) unsigned int*)(LP), 16, 0, 0)

// ============ kernel 1: weights fp32 -> bf16, lane-major granule tiles ======
// Wt layout: [kc(32k)][ntile(24)][lane(64)][8 bf16], lane = gk*16 + (n&15).
// A wave's plain coalesced dwordx4 load (addr = base + lane*16) then delivers
// lane (quad,ln) exactly granule (col=ln, k-granule=quad) -- the B-fragment
// layout MFMA wants. No LDS round-trip for W at all.
__global__ __launch_bounds__(256) void wconv_k(const float* __restrict__ Wq,
                                               const float* __restrict__ Wk,
                                               const float* __restrict__ Wv,
                                               unsigned short* __restrict__ Wt) {
  int idx = (blockIdx.x * 256 + threadIdx.x) * 4;   // 393216 elems
  int tensor = idx >> 17;
  int r = idx & 131071;
  const float* src = tensor == 0 ? Wq : (tensor == 1 ? Wk : Wv);
  float4 f = *(const float4*)(src + r);
  float sc = (tensor == 0) ? QSCALE : 1.0f;
  ushort4 o;
  o.x = f2bf(f.x * sc); o.y = f2bf(f.y * sc);
  o.z = f2bf(f.z * sc); o.w = f2bf(f.w * sc);
  int nl = r >> 10, k = r & 1023;
  int n = tensor * 128 + nl;
  int kc = k >> 5, kl = k & 31, gk = kl >> 3, j = kl & 7;  // j in {0,4}
  int ntile = n >> 4;
  int lane_slot = gk * 16 + (n & 15);
  *(ushort4*)(Wt + kc * 12288 + ntile * 512 + lane_slot * 8 + j) = o;
}

// ============ kernel 2: QKV projection GEMM (M=16384, N=384, K=1024) ========
// v6: BM=32 x N-half=192, grid 1024 (was BM=64/512). v5's counters showed a
// latency-bound kernel at 2 blocks/CU = 2 waves/SIMD (Occupancy 14%): three
// different sync structures all landed 46-52us with every pipe <31%, so the
// limiter is resident-wave TLP, not the schedule. Halving BM doubles the
// grid -> 4 blocks/CU (16 waves/CU): independent blocks cover each other's
// vmcnt/barrier waits. LDS 4 x 4KB = 16KB; acc 24 VGPR. W global->VGPR
// (lane-major Wt, 4 statically-rotated reg bufs); x GLD->LDS swizzled;
// depth-3 counted vmcnt (4 loads/wave/chunk -> vmcnt(8), tail 4/0).
__global__ __launch_bounds__(256, 4) void proj_k(const float* __restrict__ x,
    const float* __restrict__ bq, const float* __restrict__ bk,
    const float* __restrict__ bv, const unsigned short* __restrict__ Wt,
    unsigned short* __restrict__ Qg, unsigned short* __restrict__ KVg) {
  __shared__ unsigned int xb[4][1024];       // 4 x 4KB: x chunk [32r][8 gx swz] fp32
  const int tid = threadIdx.x;
  const int wv = tid >> 6, ln = tid & 15, quad = (tid >> 4) & 3;
  const int lane = tid & 63;
  // bijective XCD-chunked swizzle (1024 % 8 == 0): XCD gets 128 consecutive
  // slots = 64 consecutive mt, both nh halves -> x rows shared in-XCD L2.
  const int sw = (blockIdx.x & 7) * 128 + (blockIdx.x >> 3);
  const int mt = sw >> 1;                    // 0..511: rows mt*32..+31
  const int nh = sw & 1;                     // N half: n-tiles nh*12..+11

  float bias[3];
  int tensor_[3], hcol_[3];
#pragma unroll
  for (int nt = 0; nt < 3; nt++) {
    int g_nt = nh * 12 + wv * 3 + nt;        // global n-tile 0..23
    int tensor = g_nt >> 3;
    int hcol = ((g_nt & 7) << 4) + ln;
    tensor_[nt] = tensor; hcol_[nt] = hcol;
    bias[nt] = (tensor == 0) ? bq[hcol] * QSCALE : (tensor == 1 ? bk[hcol] : bv[hcol]);
  }

  f32x4 acc[2][3];
  f32x4 zero = {0.f, 0.f, 0.f, 0.f};
#pragma unroll
  for (int m = 0; m < 2; m++)
#pragma unroll
    for (int nt = 0; nt < 3; nt++) acc[m][nt] = zero;

  // W register buffers: chunk kc lives in Wb[kc&3][*]; all indices static
  // (loop unrolled x4), so these stay in VGPRs (48 total).
  u32x4 Wb[4][3];
  const unsigned short* wpb = Wt + (nh * 12 + wv * 3) * 512 + lane * 8;

  // x DMA: 256 granules (32 rows x 8 slots of 16B); slot s holds global
  // granule gx = s ^ (row&7) (swizzle baked into per-lane global src addr).
  // One 1KB GLD per wave. W: 3 plain coalesced dwordx4 per wave per chunk,
  // straight to VGPRs. 4 vmem ops per wave per chunk total.
#define PJ_STAGE(BUF, KC)                                                      \
  {                                                                            \
    int idx = wv * 64 + lane;                                                  \
    int r_ = idx >> 3, gx = (idx & 7) ^ (r_ & 7);                              \
    GLD(x + (size_t)(mt * 32 + r_) * 1024 + (KC) * 32 + gx * 4,                \
        &xb[BUF][wv * 256]);                                                   \
  }                                                                            \
  _Pragma("unroll") for (int i = 0; i < 3; i++) {                              \
    Wb[BUF][i] = *(const u32x4*)(wpb + (size_t)(KC) * 12288 + i * 512);        \
  }

  PJ_STAGE(0, 0);
  PJ_STAGE(1, 1);
  PJ_STAGE(2, 2);
  for (int kcb = 0; kcb < 32; kcb += 4) {
#pragma unroll
    for (int u = 0; u < 4; u++) {
      const int kc = kcb + u;                // kc & 3 == u (kcb % 4 == 0)
      // Wait for chunk kc's own 4 ops only; 8 newer stay in flight.
      if (kc < 30) {
        asm volatile("s_waitcnt vmcnt(8)" ::: "memory");
      } else if (kc == 30) {
        asm volatile("s_waitcnt vmcnt(4)" ::: "memory");
      } else {
        asm volatile("s_waitcnt vmcnt(0)" ::: "memory");
      }
      __builtin_amdgcn_s_barrier();
      __builtin_amdgcn_sched_barrier(0);

      s16x8 a[2];
#pragma unroll
      for (int m = 0; m < 2; m++) {
        int r_ = m * 16 + ln;
        int c0 = (quad * 2) ^ (r_ & 7);
        int c1 = c0 ^ 1;
        f32x4 lo = *(const f32x4*)&xb[u][(r_ * 8 + c0) * 4];
        f32x4 hi = *(const f32x4*)&xb[u][(r_ * 8 + c1) * 4];
        u32x4 af;
        af.x = f2bf(lo.x) | ((unsigned)f2bf(lo.y) << 16);
        af.y = f2bf(lo.z) | ((unsigned)f2bf(lo.w) << 16);
        af.z = f2bf(hi.x) | ((unsigned)f2bf(hi.y) << 16);
        af.w = f2bf(hi.z) | ((unsigned)f2bf(hi.w) << 16);
        a[m] = __builtin_bit_cast(s16x8, af);
      }
#pragma unroll
      for (int nt = 0; nt < 3; nt++) {
        s16x8 b = __builtin_bit_cast(s16x8, Wb[u][nt]);
#pragma unroll
        for (int m = 0; m < 2; m++)
          acc[m][nt] = mfma16(a[m], b, acc[m][nt]);
      }

      // Stage chunk kc+3 into slot (u+3)&3 (chunk kc-1's slot; every wave
      // passed barrier(kc), so all reads of that slot are done). Reg buffer
      // WAR is safe: MFMAs reading Wb[(u+3)&3] issued before these loads.
      if (kc <= 28) { PJ_STAGE((u + 3) & 3, kc + 3); }
    }
  }

  // epilogue: C-layout row = quad*4+reg (+m*16), col = ln (m89-verified).
  // K tile elem (tr,h): (tr*16 + ghs)*8 + (h&7), ghs = (gh&8)|((gh&7)^(tr&7))
  // V tile elem (tr,h): 4096 + (h*4 + gts)*8 + (tr&7), gts = (tr>>3)^((h>>1)&3)
  const int r0 = mt * 32;
#pragma unroll
  for (int nt = 0; nt < 3; nt++) {
    int hcol = hcol_[nt];
#pragma unroll
    for (int m = 0; m < 2; m++) {
#pragma unroll
      for (int reg = 0; reg < 4; reg++) {
        float val = acc[m][nt][reg] + bias[nt];
        unsigned short h = f2bf(val);
        int rl = m * 16 + quad * 4 + reg;       // 0..31 == tr
        int t_abs = r0 + rl;
        int tr = rl;                             // row within 32-key chunk
        size_t chbase = (size_t)((t_abs >> 12) * 128 + ((t_abs & 4095) >> 5)) * 8192;
        if (tensor_[nt] == 0) {
          Qg[(size_t)t_abs * 128 + hcol] = h;
        } else if (tensor_[nt] == 1) {
          int gh = hcol >> 3;
          int ghs = (gh & 8) | ((gh & 7) ^ (tr & 7));
          KVg[chbase + (tr * 16 + ghs) * 8 + (hcol & 7)] = h;
        } else {
          int gts = (tr >> 3) ^ ((hcol >> 1) & 3);
          KVg[chbase + 4096 + (hcol * 4 + gts) * 8 + (tr & 7)] = h;
        }
      }
    }
  }
}

// ============ kernel 3: causal attention, DMA-pipelined, no-max softmax =====
// BM=128 (4 waves x 32 rows), BN=32, seg=16 chunks, dense 576-block grid.
// XCD-chunked block swizzle (each XCD owns 72 consecutive slots = 2MB of one
// batch's KV, L2-resident). id is used for BOTH (b,qt,seg) decode and Po/Plr
// slot index, so combine_k is unchanged.
__global__ __launch_bounds__(256, 3) void attn_k(const unsigned short* __restrict__ Qg,
    const unsigned short* __restrict__ KVg,
    unsigned short* __restrict__ Po, float* __restrict__ Plr) {
  __shared__ unsigned short kvb[2][8192];  // 2 x 16KB (K tile 8KB | V tile 8KB)
  __shared__ unsigned short Pl[128 * 40];  // 10KB, wave-private rows
  const int tid = threadIdx.x;
  const int wv = tid >> 6, ln = tid & 15, quad = (tid >> 4) & 3;
  const int lane = tid & 63;
  const int id = (blockIdx.x & 7) * 72 + (blockIdx.x >> 3);  // XCD-chunked slot
  const int b = id / 144;
  int rem = id - b * 144;
  int a_ = 0;
  while (2 * (a_ + 1) * (a_ + 2) <= rem) a_++;       // <=7 scalar iters
  const int off = rem - 2 * a_ * (a_ + 1);
  const int qt = 4 * a_ + off / (a_ + 1);
  const int seg = off - (off / (a_ + 1)) * (a_ + 1);
  const int qbase = qt * 128;
  const int totch = 4 * qt + 4;
  const int nch = min(16, totch - seg * 16);

  const unsigned short* KVb = KVg + (size_t)b * 1048576;  // 128 chunks x 8192 elems

  // Q fragments: 2 m-tiles, A-layout (m=ln, k=quad*8+j + 32*ks)
  u32x4 qf[2][4];
#pragma unroll
  for (int m = 0; m < 2; m++) {
    const int qrow = b * 4096 + qbase + wv * 32 + m * 16 + ln;
#pragma unroll
    for (int ks = 0; ks < 4; ks++)
      qf[m][ks] = *(const u32x4*)((const char*)Qg + (size_t)qrow * 256 + ks * 64 + quad * 16);
  }

  f32x4 o[2][8];
  f32x4 lacc[2];
  f32x4 zero = {0.f, 0.f, 0.f, 0.f};
#pragma unroll
  for (int m = 0; m < 2; m++) {
    lacc[m] = zero;
#pragma unroll
    for (int i = 0; i < 8; i++) o[m][i] = zero;
  }
  const s16x8 onesb = {0x3F80, 0x3F80, 0x3F80, 0x3F80, 0x3F80, 0x3F80, 0x3F80, 0x3F80};

#define ATTN_DMA(BUF, CH)                                                      \
  _Pragma("unroll") for (int i = 0; i < 4; i++) {                              \
    GLD(KVb + (size_t)(CH) * 8192 + (wv * 4 + i) * 512 + lane * 8,             \
        &kvb[BUF][(wv * 4 + i) * 512]);                                        \
  }

  ATTN_DMA(0, seg * 16);
  for (int ci = 0; ci < nch; ci++) {
    const int cur = ci & 1;
    const int ch = seg * 16 + ci;
    const int t0 = ch * 32;
    __syncthreads();                 // DMA(cur) visible; prior reads of cur done
    if (ci + 1 < nch) { ATTN_DMA(cur ^ 1, ch + 1); }

    // S = Q K^T; K frag (t = nt*16+ln, granule gh = ks*4+quad, swizzled)
    f32x4 s[2][2];
#pragma unroll
    for (int m = 0; m < 2; m++)
#pragma unroll
      for (int nt = 0; nt < 2; nt++) s[m][nt] = zero;
#pragma unroll
    for (int ks = 0; ks < 4; ks++)
#pragma unroll
      for (int nt = 0; nt < 2; nt++) {
        int t = nt * 16 + ln;
        int gh = ks * 4 + quad;
        int ghs = (gh & 8) | ((gh & 7) ^ (t & 7));
        s16x8 kf = __builtin_bit_cast(s16x8, *(const u32x4*)&kvb[cur][(t * 16 + ghs) * 8]);
#pragma unroll
        for (int m = 0; m < 2; m++)
          s[m][nt] = mfma16(__builtin_bit_cast(s16x8, qf[m][ks]), kf, s[m][nt]);
      }

    // causal mask (diagonal-touching chunks; fully-masked chunks -> p=0)
    if (t0 + 31 > qbase + wv * 32) {
#pragma unroll
      for (int m = 0; m < 2; m++)
#pragma unroll
        for (int nt = 0; nt < 2; nt++)
#pragma unroll
          for (int reg = 0; reg < 4; reg++) {
            int kidx = t0 + nt * 16 + ln;
            int qidx = qbase + wv * 32 + m * 16 + quad * 4 + reg;
            if (kidx > qidx) s[m][nt][reg] = -1e30f;
          }
    }

    // p = exp2(s) -> bf16 -> wave-private LDS (C->A layout round-trip)
#pragma unroll
    for (int m = 0; m < 2; m++)
#pragma unroll
      for (int nt = 0; nt < 2; nt++)
#pragma unroll
        for (int reg = 0; reg < 4; reg++) {
          float pv = __builtin_amdgcn_exp2f(s[m][nt][reg]);
          Pl[(wv * 32 + m * 16 + quad * 4 + reg) * 40 + nt * 16 + ln] = f2bf(pv);
        }

    // PV + l accumulation; V frag (h = nh*16+ln, granule gt = quad, swizzled)
    s16x8 pa[2];
#pragma unroll
    for (int m = 0; m < 2; m++)
      pa[m] = __builtin_bit_cast(s16x8,
          *(const u32x4*)&Pl[(wv * 32 + m * 16 + ln) * 40 + quad * 8]);
#pragma unroll
    for (int nh = 0; nh < 8; nh++) {
      int h = nh * 16 + ln;
      int gts = quad ^ ((h >> 1) & 3);
      s16x8 vf = __builtin_bit_cast(s16x8,
          *(const u32x4*)&kvb[cur][4096 + (h * 4 + gts) * 8]);
#pragma unroll
      for (int m = 0; m < 2; m++)
        o[m][nh] = mfma16(pa[m], vf, o[m][nh]);
    }
#pragma unroll
    for (int m = 0; m < 2; m++)
      lacc[m] = mfma16(pa[m], onesb, lacc[m]);
  }

  // epilogue: bf16 unnormalized partial + fp32 row sums
  unsigned short* po = Po + (size_t)id * 16384;
#pragma unroll
  for (int m = 0; m < 2; m++) {
#pragma unroll
    for (int reg = 0; reg < 4; reg++) {
      int rowl = wv * 32 + m * 16 + quad * 4 + reg;
#pragma unroll
      for (int nh = 0; nh < 8; nh++)
        po[rowl * 128 + nh * 16 + ln] = f2bf(o[m][nh][reg]);
      if (ln == 0) Plr[id * 128 + rowl] = lacc[m][reg];
    }
  }
}

// ============ kernel 4: combine bf16 partials (pure sums, coalesced) ========
__global__ __launch_bounds__(256) void combine_k(const unsigned short* __restrict__ Po,
    const float* __restrict__ Plr, float* __restrict__ out) {
  const int id = blockIdx.x;
  const int tileid = id >> 2, quarter = id & 3;
  const int qt = tileid & 31;
  const int b = tileid >> 5;
  const int a_ = qt >> 2, r_ = qt & 3;
  const int base = b * 144 + 2 * a_ * (a_ + 1) + r_ * (a_ + 1);
  const int nseg = a_ + 1;
  const int tid = threadIdx.x;
#pragma unroll
  for (int i = 0; i < 2; i++) {
    int g = quarter * 512 + i * 256 + tid;   // granule of 8 elems; 2048/tile
    int row = g >> 4;
    float acc[8] = {0.f, 0.f, 0.f, 0.f, 0.f, 0.f, 0.f, 0.f};
    float L = 0.f;
    for (int s = 0; s < nseg; s++) {
      u32x4 u = *(const u32x4*)(Po + (size_t)(base + s) * 16384 + g * 8);
      L += Plr[(base + s) * 128 + row];
      acc[0] += __builtin_bit_cast(float, u.x << 16);
      acc[1] += __builtin_bit_cast(float, u.x & 0xffff0000u);
      acc[2] += __builtin_bit_cast(float, u.y << 16);
      acc[3] += __builtin_bit_cast(float, u.y & 0xffff0000u);
      acc[4] += __builtin_bit_cast(float, u.z << 16);
      acc[5] += __builtin_bit_cast(float, u.z & 0xffff0000u);
      acc[6] += __builtin_bit_cast(float, u.w << 16);
      acc[7] += __builtin_bit_cast(float, u.w & 0xffff0000u);
    }
    float inv = 1.f / L;
    float* op = out + (size_t)tileid * 16384 + g * 8;
    f32x4 o0 = {acc[0] * inv, acc[1] * inv, acc[2] * inv, acc[3] * inv};
    f32x4 o1 = {acc[4] * inv, acc[5] * inv, acc[6] * inv, acc[7] * inv};
    *(f32x4*)op = o0;
    *(f32x4*)(op + 4) = o1;
  }
}

// ============ launch ============
extern "C" void kernel_launch(void* const* d_in, const int* in_sizes, int n_in,
                              void* d_out, int out_size, void* d_ws, size_t ws_size,
                              hipStream_t stream) {
  const float* x  = (const float*)d_in[0];
  const float* Wq = (const float*)d_in[1];
  const float* bq = (const float*)d_in[2];
  const float* Wk = (const float*)d_in[3];
  const float* bk = (const float*)d_in[4];
  const float* Wv = (const float*)d_in[5];
  const float* bv = (const float*)d_in[6];
  float* out = (float*)d_out;

  char* wsb = (char*)d_ws;
  unsigned short* Wt  = (unsigned short*)wsb;                 // 768 KB (tiled W)
  unsigned short* Qg  = (unsigned short*)(wsb + 786432);      // 4 MB
  unsigned short* KVg = (unsigned short*)(wsb + 4980736);     // 8 MB (512 x 16KB tiles)
  unsigned short* Po  = (unsigned short*)(wsb + 13369344);    // 18.9 MB (576 slots, bf16)
  float* Plr = (float*)(wsb + 32243712);                      // 288 KB

  wconv_k<<<dim3(384), dim3(256), 0, stream>>>(Wq, Wk, Wv, Wt);
  proj_k<<<dim3(1024), dim3(256), 0, stream>>>(x, bq, bk, bv, Wt, Qg, KVg);
  attn_k<<<dim3(576), dim3(256), 0, stream>>>(Qg, KVg, Po, Plr);
  combine_k<<<dim3(512), dim3(256), 0, stream>>>(Po, Plr, out);
}

// Round 9
// 174.736 us; speedup vs baseline: 1.0569x; 1.0569x over previous
//
#include <hip/hip_runtime.h>
#include <stdint.h>

// ---- types ----
typedef short s16x8 __attribute__((ext_vector_type(8)));
typedef float f32x4 __attribute__((ext_vector_type(4)));
typedef unsigned int u32x4 __attribute__((ext_vector_type(4)));

// log2(e) / sqrt(128): fold softmax scale + exp2 conversion into Q projection
#define QSCALE 0.12751743f

__device__ __forceinline__ unsigned short f2bf(float f) {
  unsigned int u = __builtin_bit_cast(unsigned int, f);
  u += 0x7fffu + ((u >> 16) & 1u);   // RNE
  return (unsigned short)(u >> 16);
}

__device__ __forceinline__ f32x4 mfma16(s16x8 a, s16x8 b, f32x4 c) {
  return __builtin_amdgcn_mfma_f32_16x16x32_bf16(a, b, c, 0, 0, 0);
}

// async global->LDS DMA, 16B/lane, dest = wave-uniform base + lane*16
#define GLD(GP, LP)                                                            \
  __builtin_amdgcn_global_load_lds(                                            \
      (const __attribute__((address_space(1))) unsigned int*)(GP),             \
      (__attribute__((address_space(3))) unsigned int*)(LP), 16, 0, 0)

// ============ kernel 1: weights fp32 -> bf16, lane-major granule tiles ======
// Wt layout: [kc(32k)][ntile(24)][lane(64)][8 bf16], lane = gk*16 + (n&15).
// A wave's plain coalesced dwordx4 load (addr = base + lane*16) then delivers
// lane (quad,ln) exactly granule (col=ln, k-granule=quad) -- the B-fragment
// layout MFMA wants. No LDS round-trip for W at all.
__global__ __launch_bounds__(256) void wconv_k(const float* __restrict__ Wq,
                                               const float* __restrict__ Wk,
                                               const float* __restrict__ Wv,
                                               unsigned short* __restrict__ Wt) {
  int idx = (blockIdx.x * 256 + threadIdx.x) * 4;   // 393216 elems
  int tensor = idx >> 17;
  int r = idx & 131071;
  const float* src = tensor == 0 ? Wq : (tensor == 1 ? Wk : Wv);
  float4 f = *(const float4*)(src + r);
  float sc = (tensor == 0) ? QSCALE : 1.0f;
  ushort4 o;
  o.x = f2bf(f.x * sc); o.y = f2bf(f.y * sc);
  o.z = f2bf(f.z * sc); o.w = f2bf(f.w * sc);
  int nl = r >> 10, k = r & 1023;
  int n = tensor * 128 + nl;
  int kc = k >> 5, kl = k & 31, gk = kl >> 3, j = kl & 7;  // j in {0,4}
  int ntile = n >> 4;
  int lane_slot = gk * 16 + (n & 15);
  *(ushort4*)(Wt + kc * 12288 + ntile * 512 + lane_slot * 8 + j) = o;
}

// ============ kernel 2: QKV projection GEMM (M=16384, N=384, K=1024) ========
// v7: BM=128 x N-half=192, 256 blocks x 512 threads (8 waves: row-half =
// wv>>2, n-slab = wv&3). Phase-count theory: across v0..v6 the per-CU
// chunk-phase count is the only quantity tracking proj time (~1-1.7k cy fixed
// cost per barrier phase; BM=32 grid-1024 REGRESSED despite higher occupancy).
// This config keeps v5's per-phase structure byte-identical (5 mem-ops/wave/
// chunk, 12 MFMA/wave, vmcnt(10)/5/0 depth-3) but halves phases/CU: 1 block/CU
// x 32 chunks (vs 2 x 32). LDS 4 x 16KB; W global->VGPR (waves 0&4 etc. load
// identical W addresses -> L1 broadcast); XCD swizzle bijective (256%8==0).
__global__ __launch_bounds__(512, 2) void proj_k(const float* __restrict__ x,
    const float* __restrict__ bq, const float* __restrict__ bk,
    const float* __restrict__ bv, const unsigned short* __restrict__ Wt,
    unsigned short* __restrict__ Qg, unsigned short* __restrict__ KVg) {
  __shared__ unsigned int xb[4][4096];       // 4 x 16KB: x chunk [128r][8 gx swz] fp32
  const int tid = threadIdx.x;
  const int wv = tid >> 6, ln = tid & 15, quad = (tid >> 4) & 3;
  const int lane = tid & 63;
  const int rh = wv >> 2;                    // row half 0/1 (rows rh*64..+63)
  const int ns = wv & 3;                     // n-slab 0..3 (3 n-tiles each)
  // bijective XCD-chunked swizzle (256 % 8 == 0): XCD gets 32 consecutive
  // slots = 16 consecutive mt, both nh halves -> x rows shared in-XCD L2.
  const int sw = (blockIdx.x & 7) * 32 + (blockIdx.x >> 3);
  const int mt = sw >> 1;                    // 0..127: rows mt*128..+127
  const int nh = sw & 1;                     // N half: n-tiles nh*12..+11

  float bias[3];
  int tensor_[3], hcol_[3];
#pragma unroll
  for (int nt = 0; nt < 3; nt++) {
    int g_nt = nh * 12 + ns * 3 + nt;        // global n-tile 0..23
    int tensor = g_nt >> 3;
    int hcol = ((g_nt & 7) << 4) + ln;
    tensor_[nt] = tensor; hcol_[nt] = hcol;
    bias[nt] = (tensor == 0) ? bq[hcol] * QSCALE : (tensor == 1 ? bk[hcol] : bv[hcol]);
  }

  f32x4 acc[4][3];
  f32x4 zero = {0.f, 0.f, 0.f, 0.f};
#pragma unroll
  for (int m = 0; m < 4; m++)
#pragma unroll
    for (int nt = 0; nt < 3; nt++) acc[m][nt] = zero;

  // W register buffers: chunk kc lives in Wb[kc&3][*]; all indices static
  // (loop unrolled x4), so these stay in VGPRs (48 total).
  u32x4 Wb[4][3];
  const unsigned short* wpb = Wt + (nh * 12 + ns * 3) * 512 + lane * 8;

  // x DMA: 1024 granules (128 rows x 8 slots of 16B); slot s holds global
  // granule gx = s ^ (row&7) (swizzle baked into per-lane global src addr).
  // 2 GLD per wave. W: 3 plain coalesced dwordx4 per wave per chunk, straight
  // to VGPRs. 5 vmem ops per wave per chunk total (identical to v5).
#define PJ_STAGE(BUF, KC)                                                      \
  _Pragma("unroll") for (int i = 0; i < 2; i++) {                              \
    int idx = wv * 128 + i * 64 + lane;                                        \
    int r_ = idx >> 3, gx = (idx & 7) ^ (r_ & 7);                              \
    GLD(x + (size_t)(mt * 128 + r_) * 1024 + (KC) * 32 + gx * 4,               \
        &xb[BUF][(wv * 128 + i * 64) * 4]);                                    \
  }                                                                            \
  _Pragma("unroll") for (int i = 0; i < 3; i++) {                              \
    Wb[BUF][i] = *(const u32x4*)(wpb + (size_t)(KC) * 12288 + i * 512);        \
  }

  PJ_STAGE(0, 0);
  PJ_STAGE(1, 1);
  PJ_STAGE(2, 2);
  for (int kcb = 0; kcb < 32; kcb += 4) {
#pragma unroll
    for (int u = 0; u < 4; u++) {
      const int kc = kcb + u;                // kc & 3 == u (kcb % 4 == 0)
      // Wait for chunk kc's own 5 ops only; 10 newer stay in flight.
      if (kc < 30) {
        asm volatile("s_waitcnt vmcnt(10)" ::: "memory");
      } else if (kc == 30) {
        asm volatile("s_waitcnt vmcnt(5)" ::: "memory");
      } else {
        asm volatile("s_waitcnt vmcnt(0)" ::: "memory");
      }
      __builtin_amdgcn_s_barrier();
      __builtin_amdgcn_sched_barrier(0);

      s16x8 a[4];
#pragma unroll
      for (int m = 0; m < 4; m++) {
        int r_ = rh * 64 + m * 16 + ln;
        int c0 = (quad * 2) ^ (r_ & 7);
        int c1 = c0 ^ 1;
        f32x4 lo = *(const f32x4*)&xb[u][(r_ * 8 + c0) * 4];
        f32x4 hi = *(const f32x4*)&xb[u][(r_ * 8 + c1) * 4];
        u32x4 af;
        af.x = f2bf(lo.x) | ((unsigned)f2bf(lo.y) << 16);
        af.y = f2bf(lo.z) | ((unsigned)f2bf(lo.w) << 16);
        af.z = f2bf(hi.x) | ((unsigned)f2bf(hi.y) << 16);
        af.w = f2bf(hi.z) | ((unsigned)f2bf(hi.w) << 16);
        a[m] = __builtin_bit_cast(s16x8, af);
      }
#pragma unroll
      for (int nt = 0; nt < 3; nt++) {
        s16x8 b = __builtin_bit_cast(s16x8, Wb[u][nt]);
#pragma unroll
        for (int m = 0; m < 4; m++)
          acc[m][nt] = mfma16(a[m], b, acc[m][nt]);
      }

      // Stage chunk kc+3 into slot (u+3)&3 (chunk kc-1's slot; every wave
      // passed barrier(kc), so all reads of that slot are done). Reg buffer
      // WAR is safe: MFMAs reading Wb[(u+3)&3] issued before these loads.
      if (kc <= 28) { PJ_STAGE((u + 3) & 3, kc + 3); }
    }
  }

  // epilogue: C-layout row = quad*4+reg (+m*16 +rh*64), col = ln.
  // K tile elem (tr,h): (tr*16 + ghs)*8 + (h&7), ghs = (gh&8)|((gh&7)^(tr&7))
  // V tile elem (tr,h): 4096 + (h*4 + gts)*8 + (tr&7), gts = (tr>>3)^((h>>1)&3)
  const int r0 = mt * 128;
#pragma unroll
  for (int nt = 0; nt < 3; nt++) {
    int hcol = hcol_[nt];
#pragma unroll
    for (int m = 0; m < 4; m++) {
#pragma unroll
      for (int reg = 0; reg < 4; reg++) {
        float val = acc[m][nt][reg] + bias[nt];
        unsigned short h = f2bf(val);
        int rl = rh * 64 + m * 16 + quad * 4 + reg;   // 0..127
        int t_abs = r0 + rl;
        int tr = rl & 31;                              // row within 32-key chunk
        size_t chbase = (size_t)((t_abs >> 12) * 128 + ((t_abs & 4095) >> 5)) * 8192;
        if (tensor_[nt] == 0) {
          Qg[(size_t)t_abs * 128 + hcol] = h;
        } else if (tensor_[nt] == 1) {
          int gh = hcol >> 3;
          int ghs = (gh & 8) | ((gh & 7) ^ (tr & 7));
          KVg[chbase + (tr * 16 + ghs) * 8 + (hcol & 7)] = h;
        } else {
          int gts = (tr >> 3) ^ ((hcol >> 1) & 3);
          KVg[chbase + 4096 + (hcol * 4 + gts) * 8 + (tr & 7)] = h;
        }
      }
    }
  }
}

// ============ kernel 3: causal attention, DMA-pipelined, no-max softmax =====
// BM=128 (4 waves x 32 rows), BN=32, seg=16 chunks, dense 576-block grid.
// XCD-chunked block swizzle (each XCD owns 72 consecutive slots = 2MB of one
// batch's KV, L2-resident). id is used for BOTH (b,qt,seg) decode and Po/Plr
// slot index, so combine_k is unchanged.
__global__ __launch_bounds__(256, 3) void attn_k(const unsigned short* __restrict__ Qg,
    const unsigned short* __restrict__ KVg,
    unsigned short* __restrict__ Po, float* __restrict__ Plr) {
  __shared__ unsigned short kvb[2][8192];  // 2 x 16KB (K tile 8KB | V tile 8KB)
  __shared__ unsigned short Pl[128 * 40];  // 10KB, wave-private rows
  const int tid = threadIdx.x;
  const int wv = tid >> 6, ln = tid & 15, quad = (tid >> 4) & 3;
  const int lane = tid & 63;
  const int id = (blockIdx.x & 7) * 72 + (blockIdx.x >> 3);  // XCD-chunked slot
  const int b = id / 144;
  int rem = id - b * 144;
  int a_ = 0;
  while (2 * (a_ + 1) * (a_ + 2) <= rem) a_++;       // <=7 scalar iters
  const int off = rem - 2 * a_ * (a_ + 1);
  const int qt = 4 * a_ + off / (a_ + 1);
  const int seg = off - (off / (a_ + 1)) * (a_ + 1);
  const int qbase = qt * 128;
  const int totch = 4 * qt + 4;
  const int nch = min(16, totch - seg * 16);

  const unsigned short* KVb = KVg + (size_t)b * 1048576;  // 128 chunks x 8192 elems

  // Q fragments: 2 m-tiles, A-layout (m=ln, k=quad*8+j + 32*ks)
  u32x4 qf[2][4];
#pragma unroll
  for (int m = 0; m < 2; m++) {
    const int qrow = b * 4096 + qbase + wv * 32 + m * 16 + ln;
#pragma unroll
    for (int ks = 0; ks < 4; ks++)
      qf[m][ks] = *(const u32x4*)((const char*)Qg + (size_t)qrow * 256 + ks * 64 + quad * 16);
  }

  f32x4 o[2][8];
  f32x4 lacc[2];
  f32x4 zero = {0.f, 0.f, 0.f, 0.f};
#pragma unroll
  for (int m = 0; m < 2; m++) {
    lacc[m] = zero;
#pragma unroll
    for (int i = 0; i < 8; i++) o[m][i] = zero;
  }
  const s16x8 onesb = {0x3F80, 0x3F80, 0x3F80, 0x3F80, 0x3F80, 0x3F80, 0x3F80, 0x3F80};

#define ATTN_DMA(BUF, CH)                                                      \
  _Pragma("unroll") for (int i = 0; i < 4; i++) {                              \
    GLD(KVb + (size_t)(CH) * 8192 + (wv * 4 + i) * 512 + lane * 8,             \
        &kvb[BUF][(wv * 4 + i) * 512]);                                        \
  }

  ATTN_DMA(0, seg * 16);
  for (int ci = 0; ci < nch; ci++) {
    const int cur = ci & 1;
    const int ch = seg * 16 + ci;
    const int t0 = ch * 32;
    __syncthreads();                 // DMA(cur) visible; prior reads of cur done
    if (ci + 1 < nch) { ATTN_DMA(cur ^ 1, ch + 1); }

    // S = Q K^T; K frag (t = nt*16+ln, granule gh = ks*4+quad, swizzled)
    f32x4 s[2][2];
#pragma unroll
    for (int m = 0; m < 2; m++)
#pragma unroll
      for (int nt = 0; nt < 2; nt++) s[m][nt] = zero;
#pragma unroll
    for (int ks = 0; ks < 4; ks++)
#pragma unroll
      for (int nt = 0; nt < 2; nt++) {
        int t = nt * 16 + ln;
        int gh = ks * 4 + quad;
        int ghs = (gh & 8) | ((gh & 7) ^ (t & 7));
        s16x8 kf = __builtin_bit_cast(s16x8, *(const u32x4*)&kvb[cur][(t * 16 + ghs) * 8]);
#pragma unroll
        for (int m = 0; m < 2; m++)
          s[m][nt] = mfma16(__builtin_bit_cast(s16x8, qf[m][ks]), kf, s[m][nt]);
      }

    // causal mask (diagonal-touching chunks; fully-masked chunks -> p=0)
    if (t0 + 31 > qbase + wv * 32) {
#pragma unroll
      for (int m = 0; m < 2; m++)
#pragma unroll
        for (int nt = 0; nt < 2; nt++)
#pragma unroll
          for (int reg = 0; reg < 4; reg++) {
            int kidx = t0 + nt * 16 + ln;
            int qidx = qbase + wv * 32 + m * 16 + quad * 4 + reg;
            if (kidx > qidx) s[m][nt][reg] = -1e30f;
          }
    }

    // p = exp2(s) -> bf16 -> wave-private LDS (C->A layout round-trip)
#pragma unroll
    for (int m = 0; m < 2; m++)
#pragma unroll
      for (int nt = 0; nt < 2; nt++)
#pragma unroll
        for (int reg = 0; reg < 4; reg++) {
          float pv = __builtin_amdgcn_exp2f(s[m][nt][reg]);
          Pl[(wv * 32 + m * 16 + quad * 4 + reg) * 40 + nt * 16 + ln] = f2bf(pv);
        }

    // PV + l accumulation; V frag (h = nh*16+ln, granule gt = quad, swizzled)
    s16x8 pa[2];
#pragma unroll
    for (int m = 0; m < 2; m++)
      pa[m] = __builtin_bit_cast(s16x8,
          *(const u32x4*)&Pl[(wv * 32 + m * 16 + ln) * 40 + quad * 8]);
#pragma unroll
    for (int nh = 0; nh < 8; nh++) {
      int h = nh * 16 + ln;
      int gts = quad ^ ((h >> 1) & 3);
      s16x8 vf = __builtin_bit_cast(s16x8,
          *(const u32x4*)&kvb[cur][4096 + (h * 4 + gts) * 8]);
#pragma unroll
      for (int m = 0; m < 2; m++)
        o[m][nh] = mfma16(pa[m], vf, o[m][nh]);
    }
#pragma unroll
    for (int m = 0; m < 2; m++)
      lacc[m] = mfma16(pa[m], onesb, lacc[m]);
  }

  // epilogue: bf16 unnormalized partial + fp32 row sums
  unsigned short* po = Po + (size_t)id * 16384;
#pragma unroll
  for (int m = 0; m < 2; m++) {
#pragma unroll
    for (int reg = 0; reg < 4; reg++) {
      int rowl = wv * 32 + m * 16 + quad * 4 + reg;
#pragma unroll
      for (int nh = 0; nh < 8; nh++)
        po[rowl * 128 + nh * 16 + ln] = f2bf(o[m][nh][reg]);
      if (ln == 0) Plr[id * 128 + rowl] = lacc[m][reg];
    }
  }
}

// ============ kernel 4: combine bf16 partials (pure sums, coalesced) ========
__global__ __launch_bounds__(256) void combine_k(const unsigned short* __restrict__ Po,
    const float* __restrict__ Plr, float* __restrict__ out) {
  const int id = blockIdx.x;
  const int tileid = id >> 2, quarter = id & 3;
  const int qt = tileid & 31;
  const int b = tileid >> 5;
  const int a_ = qt >> 2, r_ = qt & 3;
  const int base = b * 144 + 2 * a_ * (a_ + 1) + r_ * (a_ + 1);
  const int nseg = a_ + 1;
  const int tid = threadIdx.x;
#pragma unroll
  for (int i = 0; i < 2; i++) {
    int g = quarter * 512 + i * 256 + tid;   // granule of 8 elems; 2048/tile
    int row = g >> 4;
    float acc[8] = {0.f, 0.f, 0.f, 0.f, 0.f, 0.f, 0.f, 0.f};
    float L = 0.f;
    for (int s = 0; s < nseg; s++) {
      u32x4 u = *(const u32x4*)(Po + (size_t)(base + s) * 16384 + g * 8);
      L += Plr[(base + s) * 128 + row];
      acc[0] += __builtin_bit_cast(float, u.x << 16);
      acc[1] += __builtin_bit_cast(float, u.x & 0xffff0000u);
      acc[2] += __builtin_bit_cast(float, u.y << 16);
      acc[3] += __builtin_bit_cast(float, u.y & 0xffff0000u);
      acc[4] += __builtin_bit_cast(float, u.z << 16);
      acc[5] += __builtin_bit_cast(float, u.z & 0xffff0000u);
      acc[6] += __builtin_bit_cast(float, u.w << 16);
      acc[7] += __builtin_bit_cast(float, u.w & 0xffff0000u);
    }
    float inv = 1.f / L;
    float* op = out + (size_t)tileid * 16384 + g * 8;
    f32x4 o0 = {acc[0] * inv, acc[1] * inv, acc[2] * inv, acc[3] * inv};
    f32x4 o1 = {acc[4] * inv, acc[5] * inv, acc[6] * inv, acc[7] * inv};
    *(f32x4*)op = o0;
    *(f32x4*)(op + 4) = o1;
  }
}

// ============ launch ============
extern "C" void kernel_launch(void* const* d_in, const int* in_sizes, int n_in,
                              void* d_out, int out_size, void* d_ws, size_t ws_size,
                              hipStream_t stream) {
  const float* x  = (const float*)d_in[0];
  const float* Wq = (const float*)d_in[1];
  const float* bq = (const float*)d_in[2];
  const float* Wk = (const float*)d_in[3];
  const float* bk = (const float*)d_in[4];
  const float* Wv = (const float*)d_in[5];
  const float* bv = (const float*)d_in[6];
  float* out = (float*)d_out;

  char* wsb = (char*)d_ws;
  unsigned short* Wt  = (unsigned short*)wsb;                 // 768 KB (tiled W)
  unsigned short* Qg  = (unsigned short*)(wsb + 786432);      // 4 MB
  unsigned short* KVg = (unsigned short*)(wsb + 4980736);     // 8 MB (512 x 16KB tiles)
  unsigned short* Po  = (unsigned short*)(wsb + 13369344);    // 18.9 MB (576 slots, bf16)
  float* Plr = (float*)(wsb + 32243712);                      // 288 KB

  wconv_k<<<dim3(384), dim3(256), 0, stream>>>(Wq, Wk, Wv, Wt);
  proj_k<<<dim3(256), dim3(512), 0, stream>>>(x, bq, bk, bv, Wt, Qg, KVg);
  attn_k<<<dim3(576), dim3(256), 0, stream>>>(Qg, KVg, Po, Plr);
  combine_k<<<dim3(512), dim3(256), 0, stream>>>(Po, Plr, out);
}